// Round 3
// baseline (520.452 us; speedup 1.0000x reference)
//
#include <hip/hip_runtime.h>
#include <math.h>

#define NE 8192
#define CDIM 64
#define NPIX 32768
#define HWSZ 4096
#define BIMG (CDIM * HWSZ)
#define NCHUNK 8
#define CPC (NE / NCHUNK)   /* 1024 codes per chunk */
#define BLK 256

// ---------------- esq[k] = sum(e[k]^2), numpy pairwise order (proven rounds 1-2) ---------
__global__ __launch_bounds__(256) void esq_kernel(const float* __restrict__ emb,
                                                  float* __restrict__ esq) {
    int k = blockIdx.x * 256 + threadIdx.x;
    const float4* e4 = (const float4*)(emb + (long)k * CDIM);
    float er[CDIM];
#pragma unroll
    for (int i = 0; i < 16; ++i) {
        float4 v = e4[i];
        er[4 * i + 0] = v.x; er[4 * i + 1] = v.y;
        er[4 * i + 2] = v.z; er[4 * i + 3] = v.w;
    }
    float res;
    {
#pragma clang fp contract(off)
        float r[8];
#pragma unroll
        for (int j = 0; j < 8; ++j) r[j] = er[j] * er[j];
#pragma unroll
        for (int i = 8; i < CDIM; i += 8) {
#pragma unroll
            for (int j = 0; j < 8; ++j) r[j] += er[i + j] * er[i + j];
        }
        res = ((r[0] + r[1]) + (r[2] + r[3])) + ((r[4] + r[5]) + (r[6] + r[7]));
    }
    esq[k] = res;
}

// ---------------- dist/argmin: lane = pixel, z in VGPRs, e via wave-uniform scalar loads -
__global__ __launch_bounds__(BLK, 4) void dist_kernel(const float* __restrict__ z,
                                                      const float* __restrict__ emb,
                                                      const float* __restrict__ esq,
                                                      float* __restrict__ part_d,
                                                      int* __restrict__ part_i) {
    const int tid = threadIdx.x;
    const int pix = blockIdx.x * BLK + tid;
    const int chunk = blockIdx.y;
    const int b = pix >> 12;
    const int hw = pix & (HWSZ - 1);

    // z[pix][0..63] into VGPRs; stride-HWSZ per c, lanes consecutive -> coalesced
    const float* zp = z + (long)b * BIMG + hw;
    float zr[CDIM];
#pragma unroll
    for (int c = 0; c < CDIM; ++c) zr[c] = zp[c * HWSZ];

    // zsq replicating numpy pairwise sum (proven absmax=0 in rounds 1-2)
    float zsq;
    {
#pragma clang fp contract(off)
        float r[8];
#pragma unroll
        for (int j = 0; j < 8; ++j) r[j] = zr[j] * zr[j];
#pragma unroll
        for (int i = 8; i < CDIM; i += 8) {
#pragma unroll
            for (int j = 0; j < 8; ++j) r[j] += zr[i + j] * zr[i + j];
        }
        zsq = ((r[0] + r[1]) + (r[2] + r[3])) + ((r[4] + r[5]) + (r[6] + r[7]));
    }

    const int code_base = chunk * CPC;
    float best_d = INFINITY;
    int best_i = code_base;

    // e-row address is wave-uniform (blockIdx.y + loop var) -> scalar loads (SGPRs).
#pragma unroll 1
    for (int t = 0; t < CPC; ++t) {
        const int code = code_base + t;
        const float* __restrict__ ep = emb + (long)code * CDIM;
        float d0 = 0.f, d1 = 0.f, d2 = 0.f, d3 = 0.f;
#pragma unroll
        for (int q = 0; q < 16; ++q) {
            d0 = fmaf(zr[4 * q + 0], ep[4 * q + 0], d0);
            d1 = fmaf(zr[4 * q + 1], ep[4 * q + 1], d1);
            d2 = fmaf(zr[4 * q + 2], ep[4 * q + 2], d2);
            d3 = fmaf(zr[4 * q + 3], ep[4 * q + 3], d3);
        }
        float dot = (d0 + d1) + (d2 + d3);
        float t1 = zsq + esq[code];       // uniform -> scalar load; fp32 round
        float dist = t1 - 2.0f * dot;     // 2*dot exact; single round (proven)
        if (dist < best_d) { best_d = dist; best_i = code; }  // strict < : lowest idx wins
    }

    part_d[chunk * NPIX + pix] = best_d;
    part_i[chunk * NPIX + pix] = best_i;
}

// ---------------- merge chunks, gather, STE write, indices, partial loss -----------------
__global__ __launch_bounds__(BLK) void finalize_kernel(const float* __restrict__ z,
                                                       const float* __restrict__ emb,
                                                       const float* __restrict__ part_d,
                                                       const int* __restrict__ part_i,
                                                       float* __restrict__ out,
                                                       float* __restrict__ block_loss) {
    const int tid = threadIdx.x;
    const int pix = blockIdx.x * BLK + tid;

    float best_d = part_d[pix];
    int best_i = part_i[pix];
#pragma unroll
    for (int ch = 1; ch < NCHUNK; ++ch) {
        float d = part_d[ch * NPIX + pix];
        int i = part_i[ch * NPIX + pix];
        if (d < best_d) { best_d = d; best_i = i; }  // strict <, ascending chunk ranges
    }

    const int b = pix >> 12;
    const int hw = pix & (HWSZ - 1);
    const float* zp = z + (long)b * BIMG + hw;
    const float* q = emb + (long)best_i * CDIM;
    float* op = out + (long)b * BIMG + hw;

    float lsum = 0.f;
#pragma unroll
    for (int c = 0; c < CDIM; ++c) {
        float zv = zp[c * HWSZ];
        float qv = q[c];
        float diff = qv - zv;
        op[c * HWSZ] = zv + diff;   // STE, reference roundings
        lsum += diff * diff;
    }

    out[(long)NPIX * CDIM + 1 + pix] = (float)best_i;

    __shared__ float red[BLK];
    red[tid] = lsum;
    __syncthreads();
    for (int s = BLK / 2; s > 0; s >>= 1) {
        if (tid < s) red[tid] += red[tid + s];
        __syncthreads();
    }
    if (tid == 0) block_loss[blockIdx.x] = red[0];
}

__global__ __launch_bounds__(128) void loss_kernel(const float* __restrict__ block_loss,
                                                   float* __restrict__ out) {
    __shared__ float red[128];
    const int tid = threadIdx.x;
    red[tid] = block_loss[tid];
    __syncthreads();
    for (int s = 64; s > 0; s >>= 1) {
        if (tid < s) red[tid] += red[tid + s];
        __syncthreads();
    }
    if (tid == 0) {
        float m = red[0] * (1.0f / (float)(NPIX * CDIM));
        out[(long)NPIX * CDIM] = m + 0.25f * m;
    }
}

extern "C" void kernel_launch(void* const* d_in, const int* in_sizes, int n_in,
                              void* d_out, int out_size, void* d_ws, size_t ws_size,
                              hipStream_t stream) {
    const float* z = (const float*)d_in[0];
    const float* emb = (const float*)d_in[1];
    float* out = (float*)d_out;

    char* ws = (char*)d_ws;
    float* part_d = (float*)ws;                                   // 1 MB
    int* part_i = (int*)(ws + (long)NCHUNK * NPIX * 4);           // 1 MB
    float* esq = (float*)(ws + 2L * NCHUNK * NPIX * 4);           // 32 KB
    float* block_loss = (float*)(ws + 2L * NCHUNK * NPIX * 4 + NE * 4);

    esq_kernel<<<NE / 256, 256, 0, stream>>>(emb, esq);

    dim3 gridB(NPIX / BLK, NCHUNK);
    dist_kernel<<<gridB, BLK, 0, stream>>>(z, emb, esq, part_d, part_i);

    finalize_kernel<<<NPIX / BLK, BLK, 0, stream>>>(z, emb, part_d, part_i, out, block_loss);

    loss_kernel<<<1, 128, 0, stream>>>(block_loss, out);
}